// Round 4
// baseline (627.042 us; speedup 1.0000x reference)
//
#include <hip/hip_runtime.h>
#include <hip/hip_bf16.h>
#include <hip/hip_fp16.h>

#define NTOK 2048
#define DDIM 512
#define POOLN 65536
#define HIDN 256
#define CHIDN 128
#define NTILES 512   // POOLN / 128

typedef __attribute__((ext_vector_type(8))) short short8;
typedef __attribute__((ext_vector_type(8))) unsigned short ushort8;
typedef __attribute__((ext_vector_type(4))) float f32x4;

__device__ __forceinline__ unsigned short f2bf(float f) {
  unsigned int u = __float_as_uint(f);
  unsigned int r = (u + 0x7FFFu + ((u >> 16) & 1u)) >> 16;
  return (unsigned short)r;
}
__device__ __forceinline__ float bf2f(unsigned short u) {
  return __uint_as_float(((unsigned int)u) << 16);
}
__device__ __forceinline__ void gl2lds16(const void* g, void* l) {
  __builtin_amdgcn_global_load_lds(
      (const __attribute__((address_space(1))) unsigned int*)g,
      (__attribute__((address_space(3))) unsigned int*)l, 16, 0, 0);
}
__device__ __forceinline__ float ftanh(float d) {
  float e = __expf(2.f * d);
  return (e - 1.f) * __builtin_amdgcn_rcpf(e + 1.f);
}

// ---------------- elementwise fp32 -> bf16 ----------------
__global__ void k_cvt_bf16(const float* __restrict__ in, unsigned short* __restrict__ out) {
  int i = (blockIdx.x * 256 + threadIdx.x) * 4;
  float4 v = *(const float4*)(in + i);
  ushort4 r;
  r.x = f2bf(v.x); r.y = f2bf(v.y); r.z = f2bf(v.z); r.w = f2bf(v.w);
  *(ushort4*)(out + i) = r;
}

// ---------------- transpose+convert: fp32 [K][N] -> bf16 [N][K] ----------------
__global__ void k_transpose_bf16(const float* __restrict__ src, unsigned short* __restrict__ dst,
                                 int K, int N) {
  __shared__ unsigned short s[64][72];
  int n0 = blockIdx.x * 64, k0 = blockIdx.y * 64;
  int t = threadIdx.x;
  int c = t & 63, kr = t >> 6;
  for (int i = 0; i < 16; i++) {
    int k = i * 4 + kr;
    s[c][k] = f2bf(src[(size_t)(k0 + k) * N + n0 + c]);
  }
  __syncthreads();
  for (int i = 0; i < 2; i++) {
    int idx = i * 256 + t;
    int n = idx >> 3, ch = idx & 7;
    uint4 v = *(const uint4*)&s[n][ch * 8];
    *(uint4*)(dst + (size_t)(n0 + n) * K + k0 + ch * 8) = v;
  }
}

// ---------------- MFMA GEMM: A[M,K]bf16 @ BT[N,K]bf16 ----------------
// LDS layout XOR-swizzled: LDS[row][unit u] holds global 8-elem unit (u ^ (row&7)).
// All swizzled frag offsets + staging pointers hoisted out of the k-loop.
// EPI==1: C = bf16(relu(acc + bias))
// EPI==2: candidate epilogue (all scores > T0 > 0 -> sign-free f16 key pack)
template <int EPI>
__global__ __launch_bounds__(256) void k_gemm(const unsigned short* __restrict__ A,
                                              const unsigned short* __restrict__ BT,
                                              const float* __restrict__ bias,
                                              unsigned short* __restrict__ C,
                                              int M, int N, int K,
                                              const float* __restrict__ T0,
                                              unsigned char* __restrict__ counts,
                                              unsigned int* __restrict__ cand, int slots) {
  __shared__ unsigned short Alds[128 * 64];
  __shared__ unsigned short Blds[128 * 64];
  __shared__ unsigned int lcnt[128];
  int nTiles = N >> 7, mTiles = M >> 7;
  int g = nTiles < 32 ? nTiles : 32;
  int per = mTiles * g;
  int bt = blockIdx.x;
  int grp = bt / per, rem = bt % per;
  int ni_ = rem / mTiles, mi_ = rem % mTiles;
  int m0 = mi_ << 7;
  int n0 = (grp * g + ni_) << 7;
  int t = threadIdx.x;
  int w = t >> 6, l = t & 63;
  int wRow = (w >> 1) << 6, wCol = (w & 1) << 6;

  f32x4 acc[4][4] = {};
  // swizzled staging source: lane l covers row (l>>3), global unit (l&7)^(row&7)
  int uSrc = ((l & 7) ^ ((l >> 3) & 7)) << 3;

  // hoisted staging pointers (advance by 64 elems per k-block)
  const unsigned short* aP[4];
  const unsigned short* bP[4];
#pragma unroll
  for (int i = 0; i < 4; i++) {
    int rbase = (w << 5) + (i << 3);
    int r = rbase + (l >> 3);
    aP[i] = A + (size_t)(m0 + r) * K + uSrc;
    bP[i] = BT + (size_t)(n0 + r) * K + uSrc;
  }
  // hoisted swizzled LDS frag offsets (loop-invariant: LDS rewritten in place)
  int q = l >> 4;
  int offA[4][2], offB[4][2];
#pragma unroll
  for (int mi = 0; mi < 4; mi++) {
    int rA = wRow + (mi << 4) + (l & 15);
    offA[mi][0] = rA * 64 + ((q ^ (rA & 7)) << 3);
    offA[mi][1] = rA * 64 + (((q + 4) ^ (rA & 7)) << 3);
    int rB = wCol + (mi << 4) + (l & 15);
    offB[mi][0] = rB * 64 + ((q ^ (rB & 7)) << 3);
    offB[mi][1] = rB * 64 + (((q + 4) ^ (rB & 7)) << 3);
  }

  for (int kb = 0; kb < K; kb += 64) {
#pragma unroll
    for (int i = 0; i < 4; i++) {
      int rbase = (w << 5) + (i << 3);
      gl2lds16(aP[i], &Alds[rbase << 6]);
      gl2lds16(bP[i], &Blds[rbase << 6]);
      aP[i] += 64;
      bP[i] += 64;
    }
    __syncthreads();
#pragma unroll
    for (int ks = 0; ks < 2; ks++) {
      short8 af[4], bfr[4];
#pragma unroll
      for (int mi = 0; mi < 4; mi++) af[mi] = *(const short8*)&Alds[offA[mi][ks]];
#pragma unroll
      for (int ni = 0; ni < 4; ni++) bfr[ni] = *(const short8*)&Blds[offB[ni][ks]];
#pragma unroll
      for (int mi = 0; mi < 4; mi++)
#pragma unroll
        for (int ni = 0; ni < 4; ni++)
          acc[mi][ni] = __builtin_amdgcn_mfma_f32_16x16x32_bf16(af[mi], bfr[ni], acc[mi][ni], 0, 0, 0);
    }
    __syncthreads();
  }

  int quad = (l >> 4) << 2;
  if (EPI == 1) {
#pragma unroll
    for (int ni = 0; ni < 4; ni++) {
      int col = n0 + wCol + (ni << 4) + (l & 15);
      float bv = bias[col];
#pragma unroll
      for (int mi = 0; mi < 4; mi++) {
        int row = m0 + wRow + (mi << 4) + quad;
#pragma unroll
        for (int r = 0; r < 4; r++) {
          float v = acc[mi][ni][r] + bv;
          v = v > 0.f ? v : 0.f;
          C[(size_t)(row + r) * N + col] = f2bf(v);
        }
      }
    }
  } else {
    if (t < 128) lcnt[t] = 0;
    __syncthreads();
    int tileIdx = n0 >> 7;
    float4 t0q[4];
    unsigned int colPack[4];
    float bv[4];
#pragma unroll
    for (int mi = 0; mi < 4; mi++)
      t0q[mi] = *(const float4*)&T0[m0 + wRow + (mi << 4) + quad];
#pragma unroll
    for (int ni = 0; ni < 4; ni++) {
      int col = n0 + wCol + (ni << 4) + (l & 15);
      colPack[ni] = (unsigned int)col ^ 0xFFFFu;
      bv[ni] = bias[col];
    }
    unsigned int* candB = cand + ((size_t)m0 * NTILES + tileIdx) * slots;
    size_t rowStride = (size_t)NTILES * slots;
#pragma unroll
    for (int ni = 0; ni < 4; ni++) {
#pragma unroll
      for (int mi = 0; mi < 4; mi++) {
#pragma unroll
        for (int r = 0; r < 4; r++) {
          float v = acc[mi][ni][r] + bv[ni];
          float thr = r == 0 ? t0q[mi].x : r == 1 ? t0q[mi].y : r == 2 ? t0q[mi].z : t0q[mi].w;
          if (v > thr) {
            int lrow = wRow + (mi << 4) + quad + r;
            _Float16 hf = (_Float16)v;  // positive: ordered without sign fixup
            unsigned int key = (unsigned int)*(unsigned short*)&hf | 0x8000u;
            unsigned int p = (key << 16) | colPack[ni];
            unsigned int pos = atomicAdd(&lcnt[lrow], 1u);
            if (pos < (unsigned int)slots) candB[(size_t)lrow * rowStride + pos] = p;
          }
        }
      }
    }
    __syncthreads();
    if (t < 128) {
      unsigned int c = lcnt[t];
      counts[(size_t)(m0 + t) * NTILES + tileIdx] =
          (unsigned char)(c < (unsigned int)slots ? c : (unsigned int)slots);
    }
  }
}

// ---------------- router GEMV ----------------
__global__ void k_router(const unsigned short* __restrict__ h1, const float* __restrict__ Wc2,
                         const float* __restrict__ bc2, int* __restrict__ budgets) {
  int t = threadIdx.x, w = t >> 6, l = t & 63;
  int row = blockIdx.x * 4 + w;
  float v = bf2f(h1[row * 128 + l]) * Wc2[l] + bf2f(h1[row * 128 + 64 + l]) * Wc2[64 + l];
  for (int o = 1; o < 64; o <<= 1) v += __shfl_xor(v, o);
  if (l == 0) {
    float c = 1.f / (1.f + expf(-(v + bc2[0])));
    float raw = 100.f + 156.f * c * c;
    raw = fminf(fmaxf(raw, 100.f), 256.f);
    budgets[row] = (int)rintf(raw);
  }
}

// ---------------- per-row candidate threshold: T0 = 2.0 * |h_row| / 16 ----------------
__global__ void k_thresh(const unsigned short* __restrict__ h, float* __restrict__ T0) {
  int t = threadIdx.x, w = t >> 6, l = t & 63;
  int row = blockIdx.x * 4 + w;
  float s = 0.f;
#pragma unroll
  for (int j = 0; j < 4; j++) {
    float v = bf2f(h[row * 256 + j * 64 + l]);
    s += v * v;
  }
  for (int o = 1; o < 64; o <<= 1) s += __shfl_xor(s, o);
  if (l == 0) T0[row] = 2.0f * sqrtf(s) * (1.f / 16.f);
}

// ---------------- exact top-256 select from slotted candidates + masked softmax -------
__device__ void find_bin(unsigned int* hist, int bins, unsigned int need, int t,
                         unsigned int* S, unsigned int* res) {
  int per = bins >> 8;
  unsigned int s = 0;
  for (int i = 0; i < per; i++) s += hist[t * per + i];
  S[t] = s;
  __syncthreads();
  for (int off = 1; off < 256; off <<= 1) {
    unsigned int v = (t + off < 256) ? S[t + off] : 0u;
    __syncthreads();
    S[t] += v;
    __syncthreads();
  }
  if (t == 0) { res[0] = 0u; res[1] = 0u; }
  __syncthreads();
  bool hit = (S[t] >= need) && (t == 255 || S[t + 1] < need);
  if (hit) { res[0] = (unsigned int)t; res[1] = (t == 255) ? 0u : S[t + 1]; }
  __syncthreads();
  if (t == 0) {
    int gg = (int)res[0];
    unsigned int cum = res[1];
    int binSel = gg * per;
    for (int b = gg * per + per - 1; b >= gg * per; b--) {
      unsigned int h = hist[b];
      if (cum + h >= need) { binSel = b; break; }
      cum += h;
    }
    res[0] = (unsigned int)binSel;
    res[1] = cum;
  }
  __syncthreads();
}

__global__ __launch_bounds__(256) void k_topk(const unsigned int* __restrict__ cand,
                                              const unsigned char* __restrict__ counts,
                                              int slots,
                                              const int* __restrict__ budgets,
                                              int* __restrict__ topk_idx,
                                              float* __restrict__ topk_w) {
  __shared__ unsigned int cb[4096];
  __shared__ unsigned int hist[2048];
  __shared__ unsigned int S[256];
  __shared__ unsigned int res[2];
  __shared__ unsigned int sel[256];
  __shared__ unsigned int cnt0;
  __shared__ float fred[8];
  __shared__ int sScan[256];

  int row = blockIdx.x;
  int t = threadIdx.x;

  // gather candidates: prefix-sum 512 tile counts, copy slots to cb
  const unsigned char* cr = counts + (size_t)row * NTILES;
  int c0 = cr[2 * t], c1 = cr[2 * t + 1];
  int s = c0 + c1;
  sScan[t] = s;
  __syncthreads();
  for (int off = 1; off < 256; off <<= 1) {
    int v = (t >= off) ? sScan[t - off] : 0;
    __syncthreads();
    sScan[t] += v;
    __syncthreads();
  }
  int n = sScan[255];
  if (n > 4096) n = 4096;
  int b0 = sScan[t] - s;
  const unsigned int* cdr = cand + (size_t)row * NTILES * slots;
  for (int i = 0; i < c0; i++)
    if (b0 + i < 4096) cb[b0 + i] = cdr[(2 * t) * slots + i];
  for (int i = 0; i < c1; i++)
    if (b0 + c0 + i < 4096) cb[b0 + c0 + i] = cdr[(2 * t + 1) * slots + i];
  sel[t] = 0u;
  if (t == 0) cnt0 = 0u;
  unsigned int need = (n < 256) ? (unsigned int)n : 256u;

  // L1: bits [31:22]
  for (int i = t; i < 1024; i += 256) hist[i] = 0;
  __syncthreads();
  for (int i = t; i < n; i += 256) atomicAdd(&hist[cb[i] >> 22], 1u);
  __syncthreads();
  find_bin(hist, 1024, need, t, S, res);
  unsigned int b1 = res[0], a1 = res[1];
  unsigned int need2 = need - a1;

  // L2: bits [21:11] within prefix b1
  for (int i = t; i < 2048; i += 256) hist[i] = 0;
  __syncthreads();
  for (int i = t; i < n; i += 256) {
    unsigned int p = cb[i];
    if ((p >> 22) == b1) atomicAdd(&hist[(p >> 11) & 0x7FFu], 1u);
  }
  __syncthreads();
  find_bin(hist, 2048, need2, t, S, res);
  unsigned int b2 = res[0], a2 = res[1];
  unsigned int need3 = need2 - a2;

  // L3: bits [10:0] within prefix (b1,b2)
  for (int i = t; i < 2048; i += 256) hist[i] = 0;
  __syncthreads();
  for (int i = t; i < n; i += 256) {
    unsigned int p = cb[i];
    if ((p >> 22) == b1 && ((p >> 11) & 0x7FFu) == b2) atomicAdd(&hist[p & 0x7FFu], 1u);
  }
  __syncthreads();
  find_bin(hist, 2048, need3, t, S, res);
  unsigned int T = (b1 << 22) | (b2 << 11) | res[0];
  __syncthreads();

  for (int i = t; i < n; i += 256) {
    unsigned int p = cb[i];
    if (p >= T) {
      unsigned int pos = atomicAdd(&cnt0, 1u);
      if (pos < 256u) sel[pos] = p;
    }
  }
  __syncthreads();

  // bitonic sort sel[256] descending (pads = 0 sort last)
  for (int k = 2; k <= 256; k <<= 1) {
    for (int j = k >> 1; j > 0; j >>= 1) {
      int ixj = t ^ j;
      if (ixj > t) {
        unsigned int a = sel[t], b = sel[ixj];
        bool up = ((t & k) == 0);
        bool sw = up ? (a < b) : (a > b);
        if (sw) { sel[t] = b; sel[ixj] = a; }
      }
      __syncthreads();
    }
  }

  // masked softmax
  unsigned int p = sel[t];
  unsigned int okey = p >> 16;
  int idx = (int)((p & 0xFFFFu) ^ 0xFFFFu);
  unsigned short hb = (unsigned short)((okey & 0x8000u) ? (okey ^ 0x8000u) : (~okey & 0xFFFFu));
  union { unsigned short u; _Float16 f; } cvt;
  cvt.u = hb;
  float sc = (float)cvt.f;
  if (t == 0) fred[0] = sc;
  __syncthreads();
  float m = fred[0];
  float e = expf(sc - m);
  float r = e;
  for (int o = 1; o < 64; o <<= 1) r += __shfl_xor(r, o);
  if ((t & 63) == 0) fred[1 + (t >> 6)] = r;
  __syncthreads();
  float Z = fred[1] + fred[2] + fred[3] + fred[4];
  int budget = budgets[row];
  float wgt = (t < budget) ? (e / Z) : 0.f;
  topk_idx[(size_t)row * 256 + t] = idx;
  topk_w[(size_t)row * 256 + t] = wgt;
}

// ---------------- executor: one wave per row, bf16 pool, 4 dot-chains ----------------
__global__ __launch_bounds__(256) void k_exec(const float* __restrict__ x,
                                              const unsigned short* __restrict__ poolb,
                                              const int* __restrict__ topk_idx,
                                              const float* __restrict__ topk_w,
                                              const int* __restrict__ budgets,
                                              float* __restrict__ out) {
  __shared__ int skidx[4][256];
  __shared__ float skwt[4][256];
  int t = threadIdx.x, w = t >> 6, l = t & 63;
  int row = blockIdx.x * 4 + w;
  *(int4*)&skidx[w][l * 4] = *(const int4*)&topk_idx[(size_t)row * 256 + l * 4];
  *(float4*)&skwt[w][l * 4] = *(const float4*)&topk_w[(size_t)row * 256 + l * 4];
  __syncthreads();
  int budget = budgets[row];
  int bmax = (budget + 3) & ~3;  // weights are 0 beyond budget -> branch-free tail
  const float* xr = x + (size_t)row * 512;
  float4 x0 = *(const float4*)(xr + l * 8);
  float4 x1 = *(const float4*)(xr + l * 8 + 4);
  float xv[8] = {x0.x, x0.y, x0.z, x0.w, x1.x, x1.y, x1.z, x1.w};
  float a[8] = {};
  for (int k0 = 0; k0 < bmax; k0 += 4) {
    int ka = skidx[w][k0], kb = skidx[w][k0 + 1], kc = skidx[w][k0 + 2], kd = skidx[w][k0 + 3];
    ushort8 pa = *(const ushort8*)(poolb + (size_t)ka * 512 + l * 8);
    ushort8 pb = *(const ushort8*)(poolb + (size_t)kb * 512 + l * 8);
    ushort8 pc = *(const ushort8*)(poolb + (size_t)kc * 512 + l * 8);
    ushort8 pd = *(const ushort8*)(poolb + (size_t)kd * 512 + l * 8);
    float fa[8], fb[8], fc[8], fd[8];
#pragma unroll
    for (int j = 0; j < 8; j++) {
      fa[j] = bf2f(pa[j]); fb[j] = bf2f(pb[j]); fc[j] = bf2f(pc[j]); fd[j] = bf2f(pd[j]);
    }
    float da = 0.f, db = 0.f, dc = 0.f, dd = 0.f;
#pragma unroll
    for (int j = 0; j < 8; j++) {
      da += fa[j] * xv[j]; db += fb[j] * xv[j]; dc += fc[j] * xv[j]; dd += fd[j] * xv[j];
    }
    for (int o = 1; o < 64; o <<= 1) {
      da += __shfl_xor(da, o);
      db += __shfl_xor(db, o);
      dc += __shfl_xor(dc, o);
      dd += __shfl_xor(dd, o);
    }
    float wa = skwt[w][k0] * ftanh(da);
    float wb = skwt[w][k0 + 1] * ftanh(db);
    float wc = skwt[w][k0 + 2] * ftanh(dc);
    float wd = skwt[w][k0 + 3] * ftanh(dd);
#pragma unroll
    for (int j = 0; j < 8; j++)
      a[j] += wa * fa[j] + wb * fb[j] + wc * fc[j] + wd * fd[j];
  }
  float4 o0 = {xv[0] + a[0], xv[1] + a[1], xv[2] + a[2], xv[3] + a[3]};
  float4 o1 = {xv[4] + a[4], xv[5] + a[5], xv[6] + a[6], xv[7] + a[7]};
  *(float4*)(out + (size_t)row * 512 + l * 8) = o0;
  *(float4*)(out + (size_t)row * 512 + l * 8 + 4) = o1;
}

extern "C" void kernel_launch(void* const* d_in, const int* in_sizes, int n_in,
                              void* d_out, int out_size, void* d_ws, size_t ws_size,
                              hipStream_t stream) {
  const float* x    = (const float*)d_in[0];
  const float* pool = (const float*)d_in[1];
  const float* Wc1  = (const float*)d_in[2];
  const float* bc1  = (const float*)d_in[3];
  const float* Wc2  = (const float*)d_in[4];
  const float* bc2  = (const float*)d_in[5];
  const float* Ws1  = (const float*)d_in[6];
  const float* bs1  = (const float*)d_in[7];
  const float* Ws2  = (const float*)d_in[8];
  const float* bs2  = (const float*)d_in[9];
  float* out = (float*)d_out;

  char* ws = (char*)d_ws;
  size_t off = 0;
  auto alloc = [&](size_t bytes) {
    void* p = ws + off;
    off += (bytes + 255) & ~(size_t)255;
    return p;
  };
  unsigned short* x_bf   = (unsigned short*)alloc((size_t)NTOK * DDIM * 2);
  unsigned short* wc1t   = (unsigned short*)alloc((size_t)CHIDN * DDIM * 2);
  unsigned short* ws1t   = (unsigned short*)alloc((size_t)HIDN * DDIM * 2);
  unsigned short* ws2t   = (unsigned short*)alloc((size_t)POOLN * HIDN * 2);
  unsigned short* pool_bf = (unsigned short*)alloc((size_t)POOLN * DDIM * 2);
  unsigned short* h1_bf  = (unsigned short*)alloc((size_t)NTOK * CHIDN * 2);
  unsigned short* h_bf   = (unsigned short*)alloc((size_t)NTOK * HIDN * 2);
  float*         T0      = (float*)alloc((size_t)NTOK * 4);
  unsigned char* counts  = (unsigned char*)alloc((size_t)NTOK * NTILES);
  int*   budgets  = (int*)alloc((size_t)NTOK * 4);
  int*   topk_idx = (int*)alloc((size_t)NTOK * 256 * 4);
  float* topk_w   = (float*)alloc((size_t)NTOK * 256 * 4);
  size_t per_slot = (size_t)NTOK * NTILES * 4;
  int slots = (int)((ws_size - off) / per_slot);
  if (slots > 20) slots = 20;
  if (slots < 8) slots = 8;
  unsigned int* cand = (unsigned int*)alloc((size_t)NTOK * NTILES * slots * 4);

  k_cvt_bf16<<<1024, 256, 0, stream>>>(x, x_bf);
  k_cvt_bf16<<<(POOLN * DDIM) / 1024, 256, 0, stream>>>(pool, pool_bf);
  k_transpose_bf16<<<dim3(CHIDN / 64, DDIM / 64), 256, 0, stream>>>(Wc1, wc1t, DDIM, CHIDN);
  k_transpose_bf16<<<dim3(HIDN / 64, DDIM / 64), 256, 0, stream>>>(Ws1, ws1t, DDIM, HIDN);
  k_transpose_bf16<<<dim3(POOLN / 64, HIDN / 64), 256, 0, stream>>>(Ws2, ws2t, HIDN, POOLN);

  // h1 = relu(x @ Wc1 + bc1)  [2048,128]
  k_gemm<1><<<(NTOK / 128) * (CHIDN / 128), 256, 0, stream>>>(
      x_bf, wc1t, bc1, h1_bf, NTOK, CHIDN, DDIM, nullptr, nullptr, nullptr, 0);
  k_router<<<NTOK / 4, 256, 0, stream>>>(h1_bf, Wc2, bc2, budgets);

  // h = relu(x @ Ws1 + bs1)  [2048,256]
  k_gemm<1><<<(NTOK / 128) * (HIDN / 128), 256, 0, stream>>>(
      x_bf, ws1t, bs1, h_bf, NTOK, HIDN, DDIM, nullptr, nullptr, nullptr, 0);
  k_thresh<<<NTOK / 4, 256, 0, stream>>>(h_bf, T0);

  // scorer GEMM with static-slot candidate epilogue (no global atomics, no score matrix)
  k_gemm<2><<<(NTOK / 128) * (POOLN / 128), 256, 0, stream>>>(
      h_bf, ws2t, bs2, nullptr, NTOK, POOLN, HIDN, T0, counts, cand, slots);

  k_topk<<<NTOK, 256, 0, stream>>>(cand, counts, slots, budgets, topk_idx, topk_w);
  k_exec<<<NTOK / 4, 256, 0, stream>>>(x, pool_bf, topk_idx, topk_w, budgets, out);
}

// Round 5
// 524.287 us; speedup vs baseline: 1.1960x; 1.1960x over previous
//
#include <hip/hip_runtime.h>
#include <hip/hip_bf16.h>
#include <hip/hip_fp16.h>

#define NTOK 2048
#define DDIM 512
#define POOLN 65536
#define HIDN 256
#define CHIDN 128
#define NTILES 512   // POOLN / 128

typedef __attribute__((ext_vector_type(8))) short short8;
typedef __attribute__((ext_vector_type(8))) unsigned short ushort8;
typedef __attribute__((ext_vector_type(4))) float f32x4;

__device__ __forceinline__ unsigned short f2bf(float f) {
  unsigned int u = __float_as_uint(f);
  unsigned int r = (u + 0x7FFFu + ((u >> 16) & 1u)) >> 16;
  return (unsigned short)r;
}
__device__ __forceinline__ float bf2f(unsigned short u) {
  return __uint_as_float(((unsigned int)u) << 16);
}
__device__ __forceinline__ void gl2lds16(const void* g, void* l) {
  __builtin_amdgcn_global_load_lds(
      (const __attribute__((address_space(1))) unsigned int*)g,
      (__attribute__((address_space(3))) unsigned int*)l, 16, 0, 0);
}
__device__ __forceinline__ float ftanh(float d) {
  float e = __expf(2.f * d);
  return (e - 1.f) * __builtin_amdgcn_rcpf(e + 1.f);
}

// ---------------- elementwise fp32 -> bf16 ----------------
__global__ void k_cvt_bf16(const float* __restrict__ in, unsigned short* __restrict__ out) {
  int i = (blockIdx.x * 256 + threadIdx.x) * 4;
  float4 v = *(const float4*)(in + i);
  ushort4 r;
  r.x = f2bf(v.x); r.y = f2bf(v.y); r.z = f2bf(v.z); r.w = f2bf(v.w);
  *(ushort4*)(out + i) = r;
}

// ---------------- transpose+convert: fp32 [K][N] -> bf16 [N][K] ----------------
__global__ void k_transpose_bf16(const float* __restrict__ src, unsigned short* __restrict__ dst,
                                 int K, int N) {
  __shared__ unsigned short s[64][72];
  int n0 = blockIdx.x * 64, k0 = blockIdx.y * 64;
  int t = threadIdx.x;
  int c = t & 63, kr = t >> 6;
  for (int i = 0; i < 16; i++) {
    int k = i * 4 + kr;
    s[c][k] = f2bf(src[(size_t)(k0 + k) * N + n0 + c]);
  }
  __syncthreads();
  for (int i = 0; i < 2; i++) {
    int idx = i * 256 + t;
    int n = idx >> 3, ch = idx & 7;
    uint4 v = *(const uint4*)&s[n][ch * 8];
    *(uint4*)(dst + (size_t)(n0 + n) * K + k0 + ch * 8) = v;
  }
}

// ---------------- MFMA GEMM: A[M,K]bf16 @ BT[N,K]bf16, K compile-time ----------------
// Round-3 proven k-loop structure (inline address recompute = latency-hiding VALU),
// K as template constant -> full unroll, const-folded addressing.
// EPI==1: C = bf16(relu(acc + bias))
// EPI==2: candidate epilogue (all scores > T0 > 0 -> sign-free f16 key pack)
template <int EPI, int KK>
__global__ __launch_bounds__(256) void k_gemm(const unsigned short* __restrict__ A,
                                              const unsigned short* __restrict__ BT,
                                              const float* __restrict__ bias,
                                              unsigned short* __restrict__ C,
                                              int M, int N,
                                              const float* __restrict__ T0,
                                              unsigned char* __restrict__ counts,
                                              unsigned int* __restrict__ cand, int slots) {
  __shared__ unsigned short Alds[128 * 64];
  __shared__ unsigned short Blds[128 * 64];
  __shared__ unsigned int lcnt[128];
  int nTiles = N >> 7, mTiles = M >> 7;
  int g = nTiles < 32 ? nTiles : 32;
  int per = mTiles * g;
  int bt = blockIdx.x;
  int grp = bt / per, rem = bt % per;
  int ni_ = rem / mTiles, mi_ = rem % mTiles;
  int m0 = mi_ << 7;
  int n0 = (grp * g + ni_) << 7;
  int t = threadIdx.x;
  int w = t >> 6, l = t & 63;
  int wRow = (w >> 1) << 6, wCol = (w & 1) << 6;

  f32x4 acc[4][4] = {};
  // swizzled staging source: lane l covers row (l>>3), global unit (l&7)^(row&7)
  int uSrc = ((l & 7) ^ ((l >> 3) & 7)) << 3;

#pragma unroll
  for (int kb = 0; kb < KK; kb += 64) {
#pragma unroll
    for (int i = 0; i < 4; i++) {
      int rbase = (w << 5) + (i << 3);
      int r = rbase + (l >> 3);
      gl2lds16(A + (size_t)(m0 + r) * KK + kb + uSrc, &Alds[rbase << 6]);
      gl2lds16(BT + (size_t)(n0 + r) * KK + kb + uSrc, &Blds[rbase << 6]);
    }
    __syncthreads();
#pragma unroll
    for (int ks = 0; ks < 64; ks += 32) {
      short8 af[4], bfr[4];
      int gU = (ks >> 3) + (l >> 4);
#pragma unroll
      for (int mi = 0; mi < 4; mi++) {
        int rA = wRow + (mi << 4) + (l & 15);
        af[mi] = *(const short8*)&Alds[rA * 64 + ((gU ^ (rA & 7)) << 3)];
      }
#pragma unroll
      for (int ni = 0; ni < 4; ni++) {
        int rB = wCol + (ni << 4) + (l & 15);
        bfr[ni] = *(const short8*)&Blds[rB * 64 + ((gU ^ (rB & 7)) << 3)];
      }
#pragma unroll
      for (int mi = 0; mi < 4; mi++)
#pragma unroll
        for (int ni = 0; ni < 4; ni++)
          acc[mi][ni] = __builtin_amdgcn_mfma_f32_16x16x32_bf16(af[mi], bfr[ni], acc[mi][ni], 0, 0, 0);
    }
    __syncthreads();
  }

  int quad = (l >> 4) << 2;
  if (EPI == 1) {
#pragma unroll
    for (int ni = 0; ni < 4; ni++) {
      int col = n0 + wCol + (ni << 4) + (l & 15);
      float bv = bias[col];
#pragma unroll
      for (int mi = 0; mi < 4; mi++) {
        int row = m0 + wRow + (mi << 4) + quad;
#pragma unroll
        for (int r = 0; r < 4; r++) {
          float v = acc[mi][ni][r] + bv;
          v = v > 0.f ? v : 0.f;
          C[(size_t)(row + r) * N + col] = f2bf(v);
        }
      }
    }
  } else {
    if (t < 128) lcnt[t] = 0;
    __syncthreads();
    int tileIdx = n0 >> 7;
    float4 t0q[4];
    unsigned int colPack[4];
    float bv[4];
#pragma unroll
    for (int mi = 0; mi < 4; mi++)
      t0q[mi] = *(const float4*)&T0[m0 + wRow + (mi << 4) + quad];
#pragma unroll
    for (int ni = 0; ni < 4; ni++) {
      int col = n0 + wCol + (ni << 4) + (l & 15);
      colPack[ni] = (unsigned int)col ^ 0xFFFFu;
      bv[ni] = bias[col];
    }
    unsigned int* candB = cand + ((size_t)m0 * NTILES + tileIdx) * slots;
    size_t rowStride = (size_t)NTILES * slots;
#pragma unroll
    for (int ni = 0; ni < 4; ni++) {
#pragma unroll
      for (int mi = 0; mi < 4; mi++) {
#pragma unroll
        for (int r = 0; r < 4; r++) {
          float v = acc[mi][ni][r] + bv[ni];
          float thr = r == 0 ? t0q[mi].x : r == 1 ? t0q[mi].y : r == 2 ? t0q[mi].z : t0q[mi].w;
          if (v > thr) {
            int lrow = wRow + (mi << 4) + quad + r;
            _Float16 hf = (_Float16)v;  // positive: ordered without sign fixup
            unsigned int key = (unsigned int)*(unsigned short*)&hf | 0x8000u;
            unsigned int p = (key << 16) | colPack[ni];
            unsigned int pos = atomicAdd(&lcnt[lrow], 1u);
            if (pos < (unsigned int)slots) candB[(size_t)lrow * rowStride + pos] = p;
          }
        }
      }
    }
    __syncthreads();
    if (t < 128) {
      unsigned int c = lcnt[t];
      counts[(size_t)(m0 + t) * NTILES + tileIdx] =
          (unsigned char)(c < (unsigned int)slots ? c : (unsigned int)slots);
    }
  }
}

// ---------------- router GEMV ----------------
__global__ void k_router(const unsigned short* __restrict__ h1, const float* __restrict__ Wc2,
                         const float* __restrict__ bc2, int* __restrict__ budgets) {
  int t = threadIdx.x, w = t >> 6, l = t & 63;
  int row = blockIdx.x * 4 + w;
  float v = bf2f(h1[row * 128 + l]) * Wc2[l] + bf2f(h1[row * 128 + 64 + l]) * Wc2[64 + l];
  for (int o = 1; o < 64; o <<= 1) v += __shfl_xor(v, o);
  if (l == 0) {
    float c = 1.f / (1.f + expf(-(v + bc2[0])));
    float raw = 100.f + 156.f * c * c;
    raw = fminf(fmaxf(raw, 100.f), 256.f);
    budgets[row] = (int)rintf(raw);
  }
}

// ---------------- per-row candidate threshold: T0 = 2.0 * |h_row| / 16 ----------------
__global__ void k_thresh(const unsigned short* __restrict__ h, float* __restrict__ T0) {
  int t = threadIdx.x, w = t >> 6, l = t & 63;
  int row = blockIdx.x * 4 + w;
  float s = 0.f;
#pragma unroll
  for (int j = 0; j < 4; j++) {
    float v = bf2f(h[row * 256 + j * 64 + l]);
    s += v * v;
  }
  for (int o = 1; o < 64; o <<= 1) s += __shfl_xor(s, o);
  if (l == 0) T0[row] = 2.0f * sqrtf(s) * (1.f / 16.f);
}

// ---------------- exact top-256 select from slotted candidates + masked softmax -------
__device__ void find_bin(unsigned int* hist, int bins, unsigned int need, int t,
                         unsigned int* S, unsigned int* res) {
  int per = bins >> 8;
  unsigned int s = 0;
  for (int i = 0; i < per; i++) s += hist[t * per + i];
  S[t] = s;
  __syncthreads();
  for (int off = 1; off < 256; off <<= 1) {
    unsigned int v = (t + off < 256) ? S[t + off] : 0u;
    __syncthreads();
    S[t] += v;
    __syncthreads();
  }
  if (t == 0) { res[0] = 0u; res[1] = 0u; }
  __syncthreads();
  bool hit = (S[t] >= need) && (t == 255 || S[t + 1] < need);
  if (hit) { res[0] = (unsigned int)t; res[1] = (t == 255) ? 0u : S[t + 1]; }
  __syncthreads();
  if (t == 0) {
    int gg = (int)res[0];
    unsigned int cum = res[1];
    int binSel = gg * per;
    for (int b = gg * per + per - 1; b >= gg * per; b--) {
      unsigned int h = hist[b];
      if (cum + h >= need) { binSel = b; break; }
      cum += h;
    }
    res[0] = (unsigned int)binSel;
    res[1] = cum;
  }
  __syncthreads();
}

__global__ __launch_bounds__(256) void k_topk(const unsigned int* __restrict__ cand,
                                              const unsigned char* __restrict__ counts,
                                              int slots,
                                              const int* __restrict__ budgets,
                                              int* __restrict__ topk_idx,
                                              float* __restrict__ topk_w) {
  __shared__ unsigned int cb[4096];
  __shared__ unsigned int hist[2048];
  __shared__ unsigned int S[256];
  __shared__ unsigned int res[2];
  __shared__ unsigned int sel[256];
  __shared__ unsigned int cnt0;
  __shared__ float fred[8];
  __shared__ int sScan[256];

  int row = blockIdx.x;
  int t = threadIdx.x;

  // gather candidates: prefix-sum 512 tile counts, copy slots to cb
  const unsigned char* cr = counts + (size_t)row * NTILES;
  int c0 = cr[2 * t], c1 = cr[2 * t + 1];
  int s = c0 + c1;
  sScan[t] = s;
  __syncthreads();
  for (int off = 1; off < 256; off <<= 1) {
    int v = (t >= off) ? sScan[t - off] : 0;
    __syncthreads();
    sScan[t] += v;
    __syncthreads();
  }
  int n = sScan[255];
  if (n > 4096) n = 4096;
  int b0 = sScan[t] - s;
  const unsigned int* cdr = cand + (size_t)row * NTILES * slots;
  for (int i = 0; i < c0; i++)
    if (b0 + i < 4096) cb[b0 + i] = cdr[(2 * t) * slots + i];
  for (int i = 0; i < c1; i++)
    if (b0 + c0 + i < 4096) cb[b0 + c0 + i] = cdr[(2 * t + 1) * slots + i];
  sel[t] = 0u;
  if (t == 0) cnt0 = 0u;
  unsigned int need = (n < 256) ? (unsigned int)n : 256u;

  // L1: bits [31:22]
  for (int i = t; i < 1024; i += 256) hist[i] = 0;
  __syncthreads();
  for (int i = t; i < n; i += 256) atomicAdd(&hist[cb[i] >> 22], 1u);
  __syncthreads();
  find_bin(hist, 1024, need, t, S, res);
  unsigned int b1 = res[0], a1 = res[1];
  unsigned int need2 = need - a1;

  // L2: bits [21:11] within prefix b1
  for (int i = t; i < 2048; i += 256) hist[i] = 0;
  __syncthreads();
  for (int i = t; i < n; i += 256) {
    unsigned int p = cb[i];
    if ((p >> 22) == b1) atomicAdd(&hist[(p >> 11) & 0x7FFu], 1u);
  }
  __syncthreads();
  find_bin(hist, 2048, need2, t, S, res);
  unsigned int b2 = res[0], a2 = res[1];
  unsigned int need3 = need2 - a2;

  // L3: bits [10:0] within prefix (b1,b2)
  for (int i = t; i < 2048; i += 256) hist[i] = 0;
  __syncthreads();
  for (int i = t; i < n; i += 256) {
    unsigned int p = cb[i];
    if ((p >> 22) == b1 && ((p >> 11) & 0x7FFu) == b2) atomicAdd(&hist[p & 0x7FFu], 1u);
  }
  __syncthreads();
  find_bin(hist, 2048, need3, t, S, res);
  unsigned int T = (b1 << 22) | (b2 << 11) | res[0];
  __syncthreads();

  for (int i = t; i < n; i += 256) {
    unsigned int p = cb[i];
    if (p >= T) {
      unsigned int pos = atomicAdd(&cnt0, 1u);
      if (pos < 256u) sel[pos] = p;
    }
  }
  __syncthreads();

  // bitonic sort sel[256] descending (pads = 0 sort last)
  for (int k = 2; k <= 256; k <<= 1) {
    for (int j = k >> 1; j > 0; j >>= 1) {
      int ixj = t ^ j;
      if (ixj > t) {
        unsigned int a = sel[t], b = sel[ixj];
        bool up = ((t & k) == 0);
        bool sw = up ? (a < b) : (a > b);
        if (sw) { sel[t] = b; sel[ixj] = a; }
      }
      __syncthreads();
    }
  }

  // masked softmax
  unsigned int p = sel[t];
  unsigned int okey = p >> 16;
  int idx = (int)((p & 0xFFFFu) ^ 0xFFFFu);
  unsigned short hb = (unsigned short)((okey & 0x8000u) ? (okey ^ 0x8000u) : (~okey & 0xFFFFu));
  union { unsigned short u; _Float16 f; } cvt;
  cvt.u = hb;
  float sc = (float)cvt.f;
  if (t == 0) fred[0] = sc;
  __syncthreads();
  float m = fred[0];
  float e = expf(sc - m);
  float r = e;
  for (int o = 1; o < 64; o <<= 1) r += __shfl_xor(r, o);
  if ((t & 63) == 0) fred[1 + (t >> 6)] = r;
  __syncthreads();
  float Z = fred[1] + fred[2] + fred[3] + fred[4];
  int budget = budgets[row];
  float wgt = (t < budget) ? (e / Z) : 0.f;
  topk_idx[(size_t)row * 256 + t] = idx;
  topk_w[(size_t)row * 256 + t] = wgt;
}

// ---------------- executor: block per row, 4 waves, bf16 pool, 4 dot-chains ----------
__global__ __launch_bounds__(256) void k_exec(const float* __restrict__ x,
                                              const unsigned short* __restrict__ poolb,
                                              const int* __restrict__ topk_idx,
                                              const float* __restrict__ topk_w,
                                              const int* __restrict__ budgets,
                                              float* __restrict__ out) {
  __shared__ float partial[4 * 512];
  __shared__ int kidx[256];
  __shared__ float kwt[256];
  int row = blockIdx.x;
  int t = threadIdx.x, w = t >> 6, l = t & 63;
  int budget = budgets[row];
  kidx[t] = topk_idx[(size_t)row * 256 + t];
  kwt[t] = topk_w[(size_t)row * 256 + t];
  __syncthreads();
  const float* xr = x + (size_t)row * 512;
  float4 x0 = *(const float4*)(xr + l * 8);
  float4 x1 = *(const float4*)(xr + l * 8 + 4);
  float xv[8] = {x0.x, x0.y, x0.z, x0.w, x1.x, x1.y, x1.z, x1.w};
  float a[8] = {};
  int bmax = (budget + 15) & ~15;  // idx[·] always valid; kwt zero beyond budget
  for (int k0 = w * 4; k0 < bmax; k0 += 16) {
    int ka = kidx[k0], kb = kidx[k0 + 1], kc = kidx[k0 + 2], kd = kidx[k0 + 3];
    ushort8 pa = *(const ushort8*)(poolb + (size_t)ka * 512 + l * 8);
    ushort8 pb = *(const ushort8*)(poolb + (size_t)kb * 512 + l * 8);
    ushort8 pc = *(const ushort8*)(poolb + (size_t)kc * 512 + l * 8);
    ushort8 pd = *(const ushort8*)(poolb + (size_t)kd * 512 + l * 8);
    float fa[8], fb[8], fc[8], fd[8];
#pragma unroll
    for (int j = 0; j < 8; j++) {
      fa[j] = bf2f(pa[j]); fb[j] = bf2f(pb[j]); fc[j] = bf2f(pc[j]); fd[j] = bf2f(pd[j]);
    }
    float da = 0.f, db = 0.f, dc = 0.f, dd = 0.f;
#pragma unroll
    for (int j = 0; j < 8; j++) {
      da += fa[j] * xv[j]; db += fb[j] * xv[j]; dc += fc[j] * xv[j]; dd += fd[j] * xv[j];
    }
    for (int o = 1; o < 64; o <<= 1) {
      da += __shfl_xor(da, o);
      db += __shfl_xor(db, o);
      dc += __shfl_xor(dc, o);
      dd += __shfl_xor(dd, o);
    }
    float wa = kwt[k0] * ftanh(da);
    float wb = kwt[k0 + 1] * ftanh(db);
    float wc = kwt[k0 + 2] * ftanh(dc);
    float wd = kwt[k0 + 3] * ftanh(dd);
#pragma unroll
    for (int j = 0; j < 8; j++)
      a[j] += wa * fa[j] + wb * fb[j] + wc * fc[j] + wd * fd[j];
  }
  *(float4*)&partial[w * 512 + l * 8] = *(float4*)&a[0];
  *(float4*)&partial[w * 512 + l * 8 + 4] = *(float4*)&a[4];
  __syncthreads();
  for (int i = 0; i < 2; i++) {
    int d = i * 256 + t;
    out[(size_t)row * 512 + d] =
        xr[d] + partial[d] + partial[512 + d] + partial[1024 + d] + partial[1536 + d];
  }
}

extern "C" void kernel_launch(void* const* d_in, const int* in_sizes, int n_in,
                              void* d_out, int out_size, void* d_ws, size_t ws_size,
                              hipStream_t stream) {
  const float* x    = (const float*)d_in[0];
  const float* pool = (const float*)d_in[1];
  const float* Wc1  = (const float*)d_in[2];
  const float* bc1  = (const float*)d_in[3];
  const float* Wc2  = (const float*)d_in[4];
  const float* bc2  = (const float*)d_in[5];
  const float* Ws1  = (const float*)d_in[6];
  const float* bs1  = (const float*)d_in[7];
  const float* Ws2  = (const float*)d_in[8];
  const float* bs2  = (const float*)d_in[9];
  float* out = (float*)d_out;

  char* ws = (char*)d_ws;
  size_t off = 0;
  auto alloc = [&](size_t bytes) {
    void* p = ws + off;
    off += (bytes + 255) & ~(size_t)255;
    return p;
  };
  unsigned short* x_bf   = (unsigned short*)alloc((size_t)NTOK * DDIM * 2);
  unsigned short* wc1t   = (unsigned short*)alloc((size_t)CHIDN * DDIM * 2);
  unsigned short* ws1t   = (unsigned short*)alloc((size_t)HIDN * DDIM * 2);
  unsigned short* ws2t   = (unsigned short*)alloc((size_t)POOLN * HIDN * 2);
  unsigned short* pool_bf = (unsigned short*)alloc((size_t)POOLN * DDIM * 2);
  unsigned short* h1_bf  = (unsigned short*)alloc((size_t)NTOK * CHIDN * 2);
  unsigned short* h_bf   = (unsigned short*)alloc((size_t)NTOK * HIDN * 2);
  float*         T0      = (float*)alloc((size_t)NTOK * 4);
  unsigned char* counts  = (unsigned char*)alloc((size_t)NTOK * NTILES);
  int*   budgets  = (int*)alloc((size_t)NTOK * 4);
  int*   topk_idx = (int*)alloc((size_t)NTOK * 256 * 4);
  float* topk_w   = (float*)alloc((size_t)NTOK * 256 * 4);
  size_t per_slot = (size_t)NTOK * NTILES * 4;
  int slots = (int)((ws_size - off) / per_slot);
  if (slots > 20) slots = 20;
  if (slots < 8) slots = 8;
  unsigned int* cand = (unsigned int*)alloc((size_t)NTOK * NTILES * slots * 4);

  k_cvt_bf16<<<1024, 256, 0, stream>>>(x, x_bf);
  k_cvt_bf16<<<(POOLN * DDIM) / 1024, 256, 0, stream>>>(pool, pool_bf);
  k_transpose_bf16<<<dim3(CHIDN / 64, DDIM / 64), 256, 0, stream>>>(Wc1, wc1t, DDIM, CHIDN);
  k_transpose_bf16<<<dim3(HIDN / 64, DDIM / 64), 256, 0, stream>>>(Ws1, ws1t, DDIM, HIDN);
  k_transpose_bf16<<<dim3(POOLN / 64, HIDN / 64), 256, 0, stream>>>(Ws2, ws2t, HIDN, POOLN);

  // h1 = relu(x @ Wc1 + bc1)  [2048,128]
  k_gemm<1, DDIM><<<(NTOK / 128) * (CHIDN / 128), 256, 0, stream>>>(
      x_bf, wc1t, bc1, h1_bf, NTOK, CHIDN, nullptr, nullptr, nullptr, 0);
  k_router<<<NTOK / 4, 256, 0, stream>>>(h1_bf, Wc2, bc2, budgets);

  // h = relu(x @ Ws1 + bs1)  [2048,256]
  k_gemm<1, DDIM><<<(NTOK / 128) * (HIDN / 128), 256, 0, stream>>>(
      x_bf, ws1t, bs1, h_bf, NTOK, HIDN, nullptr, nullptr, nullptr, 0);
  k_thresh<<<NTOK / 4, 256, 0, stream>>>(h_bf, T0);

  // scorer GEMM with static-slot candidate epilogue (no global atomics, no score matrix)
  k_gemm<2, HIDN><<<(NTOK / 128) * (POOLN / 128), 256, 0, stream>>>(
      h_bf, ws2t, bs2, nullptr, NTOK, POOLN, T0, counts, cand, slots);

  k_topk<<<NTOK, 256, 0, stream>>>(cand, counts, slots, budgets, topk_idx, topk_w);
  k_exec<<<NTOK, 256, 0, stream>>>(x, pool_bf, topk_idx, topk_w, budgets, out);
}

// Round 6
// 509.689 us; speedup vs baseline: 1.2302x; 1.0286x over previous
//
#include <hip/hip_runtime.h>
#include <hip/hip_bf16.h>
#include <hip/hip_fp16.h>

#define NTOK 2048
#define DDIM 512
#define POOLN 65536
#define HIDN 256
#define CHIDN 128
#define NTILES 512   // POOLN / 128

typedef __attribute__((ext_vector_type(8))) short short8;
typedef __attribute__((ext_vector_type(8))) unsigned short ushort8;
typedef __attribute__((ext_vector_type(4))) float f32x4;

__device__ __forceinline__ unsigned short f2bf(float f) {
  unsigned int u = __float_as_uint(f);
  unsigned int r = (u + 0x7FFFu + ((u >> 16) & 1u)) >> 16;
  return (unsigned short)r;
}
__device__ __forceinline__ float bf2f(unsigned short u) {
  return __uint_as_float(((unsigned int)u) << 16);
}
__device__ __forceinline__ void gl2lds16(const void* g, void* l) {
  __builtin_amdgcn_global_load_lds(
      (const __attribute__((address_space(1))) unsigned int*)g,
      (__attribute__((address_space(3))) unsigned int*)l, 16, 0, 0);
}
__device__ __forceinline__ float ftanh(float d) {
  float e = __expf(2.f * d);
  return (e - 1.f) * __builtin_amdgcn_rcpf(e + 1.f);
}

// ---------------- elementwise fp32 -> bf16 ----------------
__global__ void k_cvt_bf16(const float* __restrict__ in, unsigned short* __restrict__ out) {
  int i = (blockIdx.x * 256 + threadIdx.x) * 4;
  float4 v = *(const float4*)(in + i);
  ushort4 r;
  r.x = f2bf(v.x); r.y = f2bf(v.y); r.z = f2bf(v.z); r.w = f2bf(v.w);
  *(ushort4*)(out + i) = r;
}

// ---------------- transpose+convert: fp32 [K][N] -> bf16 [N][K] ----------------
__global__ void k_transpose_bf16(const float* __restrict__ src, unsigned short* __restrict__ dst,
                                 int K, int N) {
  __shared__ unsigned short s[64][72];
  int n0 = blockIdx.x * 64, k0 = blockIdx.y * 64;
  int t = threadIdx.x;
  int c = t & 63, kr = t >> 6;
  for (int i = 0; i < 16; i++) {
    int k = i * 4 + kr;
    s[c][k] = f2bf(src[(size_t)(k0 + k) * N + n0 + c]);
  }
  __syncthreads();
  for (int i = 0; i < 2; i++) {
    int idx = i * 256 + t;
    int n = idx >> 3, ch = idx & 7;
    uint4 v = *(const uint4*)&s[n][ch * 8];
    *(uint4*)(dst + (size_t)(n0 + n) * K + k0 + ch * 8) = v;
  }
}

// ---------------- MFMA GEMM: A[M,K]bf16 @ BT[N,K]bf16, K compile-time ----------------
// EPI==1: C = bf16(relu(acc + bias)); simple tile mapping (small N)
// EPI==2: candidate epilogue; XCD-aware swizzle (bt&7 = XCD round-robin heuristic):
//   each XCD owns a 64-n-tile strip, walked in 16m x 16n panels (1MB B + 1MB A -> L2-resident)
template <int EPI, int KK>
__global__ __launch_bounds__(256, 4) void k_gemm(const unsigned short* __restrict__ A,
                                                 const unsigned short* __restrict__ BT,
                                                 const float* __restrict__ bias,
                                                 unsigned short* __restrict__ C,
                                                 int M, int N,
                                                 const float* __restrict__ T0,
                                                 unsigned char* __restrict__ counts,
                                                 unsigned int* __restrict__ cand, int slots) {
  __shared__ unsigned short Alds[128 * 64];
  __shared__ unsigned short Blds[128 * 64];
  __shared__ unsigned int lcnt[128];
  int bt = blockIdx.x;
  int m0, n0;
  if (EPI == 2) {
    // 8192 blocks: xcd strip = 64 n-tiles; panels of 16m x 16n
    int xcd = bt & 7, j = bt >> 3;
    int g2 = j >> 8, r = j & 255;
    m0 = (r & 15) << 7;
    int nloc = (g2 << 4) + (r >> 4);
    n0 = ((xcd << 6) + nloc) << 7;
  } else {
    int nTiles = N >> 7, mTiles = M >> 7;
    int g = nTiles < 32 ? nTiles : 32;
    int per = mTiles * g;
    int grp = bt / per, rem = bt % per;
    int ni_ = rem / mTiles, mi_ = rem % mTiles;
    m0 = mi_ << 7;
    n0 = (grp * g + ni_) << 7;
  }
  int t = threadIdx.x;
  int w = t >> 6, l = t & 63;
  int wRow = (w >> 1) << 6, wCol = (w & 1) << 6;

  f32x4 acc[4][4] = {};
  // swizzled staging source: lane l covers row (l>>3), global unit (l&7)^(row&7)
  int uSrc = ((l & 7) ^ ((l >> 3) & 7)) << 3;

#pragma unroll
  for (int kb = 0; kb < KK; kb += 64) {
#pragma unroll
    for (int i = 0; i < 4; i++) {
      int rbase = (w << 5) + (i << 3);
      int r = rbase + (l >> 3);
      gl2lds16(A + (size_t)(m0 + r) * KK + kb + uSrc, &Alds[rbase << 6]);
      gl2lds16(BT + (size_t)(n0 + r) * KK + kb + uSrc, &Blds[rbase << 6]);
    }
    __syncthreads();
#pragma unroll
    for (int ks = 0; ks < 64; ks += 32) {
      short8 af[4], bfr[4];
      int gU = (ks >> 3) + (l >> 4);
#pragma unroll
      for (int mi = 0; mi < 4; mi++) {
        int rA = wRow + (mi << 4) + (l & 15);
        af[mi] = *(const short8*)&Alds[rA * 64 + ((gU ^ (rA & 7)) << 3)];
      }
#pragma unroll
      for (int ni = 0; ni < 4; ni++) {
        int rB = wCol + (ni << 4) + (l & 15);
        bfr[ni] = *(const short8*)&Blds[rB * 64 + ((gU ^ (rB & 7)) << 3)];
      }
#pragma unroll
      for (int mi = 0; mi < 4; mi++)
#pragma unroll
        for (int ni = 0; ni < 4; ni++)
          acc[mi][ni] = __builtin_amdgcn_mfma_f32_16x16x32_bf16(af[mi], bfr[ni], acc[mi][ni], 0, 0, 0);
    }
    __syncthreads();
  }

  int quad = (l >> 4) << 2;
  if (EPI == 1) {
#pragma unroll
    for (int ni = 0; ni < 4; ni++) {
      int col = n0 + wCol + (ni << 4) + (l & 15);
      float bv = bias[col];
#pragma unroll
      for (int mi = 0; mi < 4; mi++) {
        int row = m0 + wRow + (mi << 4) + quad;
#pragma unroll
        for (int r = 0; r < 4; r++) {
          float v = acc[mi][ni][r] + bv;
          v = v > 0.f ? v : 0.f;
          C[(size_t)(row + r) * N + col] = f2bf(v);
        }
      }
    }
  } else {
    if (t < 128) lcnt[t] = 0;
    __syncthreads();
    int tileIdx = n0 >> 7;
    float4 t0q[4];
    unsigned int colPack[4];
    float bv[4];
#pragma unroll
    for (int mi = 0; mi < 4; mi++)
      t0q[mi] = *(const float4*)&T0[m0 + wRow + (mi << 4) + quad];
#pragma unroll
    for (int ni = 0; ni < 4; ni++) {
      int col = n0 + wCol + (ni << 4) + (l & 15);
      colPack[ni] = (unsigned int)col ^ 0xFFFFu;
      bv[ni] = bias[col];
    }
    unsigned int* candB = cand + ((size_t)m0 * NTILES + tileIdx) * slots;
    size_t rowStride = (size_t)NTILES * slots;
#pragma unroll
    for (int ni = 0; ni < 4; ni++) {
#pragma unroll
      for (int mi = 0; mi < 4; mi++) {
#pragma unroll
        for (int r = 0; r < 4; r++) {
          float v = acc[mi][ni][r] + bv[ni];
          float thr = r == 0 ? t0q[mi].x : r == 1 ? t0q[mi].y : r == 2 ? t0q[mi].z : t0q[mi].w;
          if (v > thr) {
            int lrow = wRow + (mi << 4) + quad + r;
            _Float16 hf = (_Float16)v;  // positive: ordered without sign fixup
            unsigned int key = (unsigned int)*(unsigned short*)&hf | 0x8000u;
            unsigned int p = (key << 16) | colPack[ni];
            unsigned int pos = atomicAdd(&lcnt[lrow], 1u);
            if (pos < (unsigned int)slots) candB[(size_t)lrow * rowStride + pos] = p;
          }
        }
      }
    }
    __syncthreads();
    if (t < 128) {
      unsigned int c = lcnt[t];
      counts[(size_t)(m0 + t) * NTILES + tileIdx] =
          (unsigned char)(c < (unsigned int)slots ? c : (unsigned int)slots);
    }
  }
}

// ---------------- router GEMV ----------------
__global__ void k_router(const unsigned short* __restrict__ h1, const float* __restrict__ Wc2,
                         const float* __restrict__ bc2, int* __restrict__ budgets) {
  int t = threadIdx.x, w = t >> 6, l = t & 63;
  int row = blockIdx.x * 4 + w;
  float v = bf2f(h1[row * 128 + l]) * Wc2[l] + bf2f(h1[row * 128 + 64 + l]) * Wc2[64 + l];
  for (int o = 1; o < 64; o <<= 1) v += __shfl_xor(v, o);
  if (l == 0) {
    float c = 1.f / (1.f + expf(-(v + bc2[0])));
    float raw = 100.f + 156.f * c * c;
    raw = fminf(fmaxf(raw, 100.f), 256.f);
    budgets[row] = (int)rintf(raw);
  }
}

// ---------------- per-row candidate threshold: T0 = 2.0 * |h_row| / 16 ----------------
__global__ void k_thresh(const unsigned short* __restrict__ h, float* __restrict__ T0) {
  int t = threadIdx.x, w = t >> 6, l = t & 63;
  int row = blockIdx.x * 4 + w;
  float s = 0.f;
#pragma unroll
  for (int j = 0; j < 4; j++) {
    float v = bf2f(h[row * 256 + j * 64 + l]);
    s += v * v;
  }
  for (int o = 1; o < 64; o <<= 1) s += __shfl_xor(s, o);
  if (l == 0) T0[row] = 2.0f * sqrtf(s) * (1.f / 16.f);
}

// ---------------- exact top-256 select from slotted candidates + masked softmax -------
__device__ void find_bin(unsigned int* hist, int bins, unsigned int need, int t,
                         unsigned int* S, unsigned int* res) {
  int per = bins >> 8;
  unsigned int s = 0;
  for (int i = 0; i < per; i++) s += hist[t * per + i];
  S[t] = s;
  __syncthreads();
  for (int off = 1; off < 256; off <<= 1) {
    unsigned int v = (t + off < 256) ? S[t + off] : 0u;
    __syncthreads();
    S[t] += v;
    __syncthreads();
  }
  if (t == 0) { res[0] = 0u; res[1] = 0u; }
  __syncthreads();
  bool hit = (S[t] >= need) && (t == 255 || S[t + 1] < need);
  if (hit) { res[0] = (unsigned int)t; res[1] = (t == 255) ? 0u : S[t + 1]; }
  __syncthreads();
  if (t == 0) {
    int gg = (int)res[0];
    unsigned int cum = res[1];
    int binSel = gg * per;
    for (int b = gg * per + per - 1; b >= gg * per; b--) {
      unsigned int h = hist[b];
      if (cum + h >= need) { binSel = b; break; }
      cum += h;
    }
    res[0] = (unsigned int)binSel;
    res[1] = cum;
  }
  __syncthreads();
}

__global__ __launch_bounds__(256) void k_topk(const unsigned int* __restrict__ cand,
                                              const unsigned char* __restrict__ counts,
                                              int slots,
                                              const int* __restrict__ budgets,
                                              int* __restrict__ topk_idx,
                                              float* __restrict__ topk_w) {
  __shared__ unsigned int cb[4096];
  __shared__ unsigned int hist[2048];
  __shared__ unsigned int S[256];
  __shared__ unsigned int res[2];
  __shared__ unsigned int sel[256];
  __shared__ unsigned int cnt0;
  __shared__ float fred[8];
  __shared__ int sScan[256];

  int row = blockIdx.x;
  int t = threadIdx.x;

  // gather candidates: prefix-sum 512 tile counts, copy slots to cb
  const unsigned char* cr = counts + (size_t)row * NTILES;
  int c0 = cr[2 * t], c1 = cr[2 * t + 1];
  int s = c0 + c1;
  sScan[t] = s;
  __syncthreads();
  for (int off = 1; off < 256; off <<= 1) {
    int v = (t >= off) ? sScan[t - off] : 0;
    __syncthreads();
    sScan[t] += v;
    __syncthreads();
  }
  int n = sScan[255];
  if (n > 4096) n = 4096;
  int b0 = sScan[t] - s;
  const unsigned int* cdr = cand + (size_t)row * NTILES * slots;
  for (int i = 0; i < c0; i++)
    if (b0 + i < 4096) cb[b0 + i] = cdr[(2 * t) * slots + i];
  for (int i = 0; i < c1; i++)
    if (b0 + c0 + i < 4096) cb[b0 + c0 + i] = cdr[(2 * t + 1) * slots + i];
  sel[t] = 0u;
  if (t == 0) cnt0 = 0u;
  unsigned int need = (n < 256) ? (unsigned int)n : 256u;

  // L1: bits [31:22]
  for (int i = t; i < 1024; i += 256) hist[i] = 0;
  __syncthreads();
  for (int i = t; i < n; i += 256) atomicAdd(&hist[cb[i] >> 22], 1u);
  __syncthreads();
  find_bin(hist, 1024, need, t, S, res);
  unsigned int b1 = res[0], a1 = res[1];
  unsigned int need2 = need - a1;

  // L2: bits [21:11] within prefix b1
  for (int i = t; i < 2048; i += 256) hist[i] = 0;
  __syncthreads();
  for (int i = t; i < n; i += 256) {
    unsigned int p = cb[i];
    if ((p >> 22) == b1) atomicAdd(&hist[(p >> 11) & 0x7FFu], 1u);
  }
  __syncthreads();
  find_bin(hist, 2048, need2, t, S, res);
  unsigned int b2 = res[0], a2 = res[1];
  unsigned int need3 = need2 - a2;

  // L3: bits [10:0] within prefix (b1,b2)
  for (int i = t; i < 2048; i += 256) hist[i] = 0;
  __syncthreads();
  for (int i = t; i < n; i += 256) {
    unsigned int p = cb[i];
    if ((p >> 22) == b1 && ((p >> 11) & 0x7FFu) == b2) atomicAdd(&hist[p & 0x7FFu], 1u);
  }
  __syncthreads();
  find_bin(hist, 2048, need3, t, S, res);
  unsigned int T = (b1 << 22) | (b2 << 11) | res[0];
  __syncthreads();

  for (int i = t; i < n; i += 256) {
    unsigned int p = cb[i];
    if (p >= T) {
      unsigned int pos = atomicAdd(&cnt0, 1u);
      if (pos < 256u) sel[pos] = p;
    }
  }
  __syncthreads();

  // bitonic sort sel[256] descending (pads = 0 sort last)
  for (int k = 2; k <= 256; k <<= 1) {
    for (int j = k >> 1; j > 0; j >>= 1) {
      int ixj = t ^ j;
      if (ixj > t) {
        unsigned int a = sel[t], b = sel[ixj];
        bool up = ((t & k) == 0);
        bool sw = up ? (a < b) : (a > b);
        if (sw) { sel[t] = b; sel[ixj] = a; }
      }
      __syncthreads();
    }
  }

  // masked softmax
  unsigned int p = sel[t];
  unsigned int okey = p >> 16;
  int idx = (int)((p & 0xFFFFu) ^ 0xFFFFu);
  unsigned short hb = (unsigned short)((okey & 0x8000u) ? (okey ^ 0x8000u) : (~okey & 0xFFFFu));
  union { unsigned short u; _Float16 f; } cvt;
  cvt.u = hb;
  float sc = (float)cvt.f;
  if (t == 0) fred[0] = sc;
  __syncthreads();
  float m = fred[0];
  float e = expf(sc - m);
  float r = e;
  for (int o = 1; o < 64; o <<= 1) r += __shfl_xor(r, o);
  if ((t & 63) == 0) fred[1 + (t >> 6)] = r;
  __syncthreads();
  float Z = fred[1] + fred[2] + fred[3] + fred[4];
  int budget = budgets[row];
  float wgt = (t < budget) ? (e / Z) : 0.f;
  topk_idx[(size_t)row * 256 + t] = idx;
  topk_w[(size_t)row * 256 + t] = wgt;
}

// ---------------- executor: block per row, 4 waves, bf16 pool, 4 dot-chains ----------
__global__ __launch_bounds__(256) void k_exec(const float* __restrict__ x,
                                              const unsigned short* __restrict__ poolb,
                                              const int* __restrict__ topk_idx,
                                              const float* __restrict__ topk_w,
                                              const int* __restrict__ budgets,
                                              float* __restrict__ out) {
  __shared__ float partial[4 * 512];
  __shared__ int kidx[256];
  __shared__ float kwt[256];
  int row = blockIdx.x;
  int t = threadIdx.x, w = t >> 6, l = t & 63;
  int budget = budgets[row];
  kidx[t] = topk_idx[(size_t)row * 256 + t];
  kwt[t] = topk_w[(size_t)row * 256 + t];
  __syncthreads();
  const float* xr = x + (size_t)row * 512;
  float4 x0 = *(const float4*)(xr + l * 8);
  float4 x1 = *(const float4*)(xr + l * 8 + 4);
  float xv[8] = {x0.x, x0.y, x0.z, x0.w, x1.x, x1.y, x1.z, x1.w};
  float a[8] = {};
  int bmax = (budget + 15) & ~15;  // idx[·] always valid; kwt zero beyond budget
  for (int k0 = w * 4; k0 < bmax; k0 += 16) {
    int ka = kidx[k0], kb = kidx[k0 + 1], kc = kidx[k0 + 2], kd = kidx[k0 + 3];
    ushort8 pa = *(const ushort8*)(poolb + (size_t)ka * 512 + l * 8);
    ushort8 pb = *(const ushort8*)(poolb + (size_t)kb * 512 + l * 8);
    ushort8 pc = *(const ushort8*)(poolb + (size_t)kc * 512 + l * 8);
    ushort8 pd = *(const ushort8*)(poolb + (size_t)kd * 512 + l * 8);
    float fa[8], fb[8], fc[8], fd[8];
#pragma unroll
    for (int j = 0; j < 8; j++) {
      fa[j] = bf2f(pa[j]); fb[j] = bf2f(pb[j]); fc[j] = bf2f(pc[j]); fd[j] = bf2f(pd[j]);
    }
    float da = 0.f, db = 0.f, dc = 0.f, dd = 0.f;
#pragma unroll
    for (int j = 0; j < 8; j++) {
      da += fa[j] * xv[j]; db += fb[j] * xv[j]; dc += fc[j] * xv[j]; dd += fd[j] * xv[j];
    }
    for (int o = 1; o < 64; o <<= 1) {
      da += __shfl_xor(da, o);
      db += __shfl_xor(db, o);
      dc += __shfl_xor(dc, o);
      dd += __shfl_xor(dd, o);
    }
    float wa = kwt[k0] * ftanh(da);
    float wb = kwt[k0 + 1] * ftanh(db);
    float wc = kwt[k0 + 2] * ftanh(dc);
    float wd = kwt[k0 + 3] * ftanh(dd);
#pragma unroll
    for (int j = 0; j < 8; j++)
      a[j] += wa * fa[j] + wb * fb[j] + wc * fc[j] + wd * fd[j];
  }
  *(float4*)&partial[w * 512 + l * 8] = *(float4*)&a[0];
  *(float4*)&partial[w * 512 + l * 8 + 4] = *(float4*)&a[4];
  __syncthreads();
  for (int i = 0; i < 2; i++) {
    int d = i * 256 + t;
    out[(size_t)row * 512 + d] =
        xr[d] + partial[d] + partial[512 + d] + partial[1024 + d] + partial[1536 + d];
  }
}

extern "C" void kernel_launch(void* const* d_in, const int* in_sizes, int n_in,
                              void* d_out, int out_size, void* d_ws, size_t ws_size,
                              hipStream_t stream) {
  const float* x    = (const float*)d_in[0];
  const float* pool = (const float*)d_in[1];
  const float* Wc1  = (const float*)d_in[2];
  const float* bc1  = (const float*)d_in[3];
  const float* Wc2  = (const float*)d_in[4];
  const float* bc2  = (const float*)d_in[5];
  const float* Ws1  = (const float*)d_in[6];
  const float* bs1  = (const float*)d_in[7];
  const float* Ws2  = (const float*)d_in[8];
  const float* bs2  = (const float*)d_in[9];
  float* out = (float*)d_out;

  char* ws = (char*)d_ws;
  size_t off = 0;
  auto alloc = [&](size_t bytes) {
    void* p = ws + off;
    off += (bytes + 255) & ~(size_t)255;
    return p;
  };
  unsigned short* x_bf   = (unsigned short*)alloc((size_t)NTOK * DDIM * 2);
  unsigned short* wc1t   = (unsigned short*)alloc((size_t)CHIDN * DDIM * 2);
  unsigned short* ws1t   = (unsigned short*)alloc((size_t)HIDN * DDIM * 2);
  unsigned short* ws2t   = (unsigned short*)alloc((size_t)POOLN * HIDN * 2);
  unsigned short* pool_bf = (unsigned short*)alloc((size_t)POOLN * DDIM * 2);
  unsigned short* h1_bf  = (unsigned short*)alloc((size_t)NTOK * CHIDN * 2);
  unsigned short* h_bf   = (unsigned short*)alloc((size_t)NTOK * HIDN * 2);
  float*         T0      = (float*)alloc((size_t)NTOK * 4);
  unsigned char* counts  = (unsigned char*)alloc((size_t)NTOK * NTILES);
  int*   budgets  = (int*)alloc((size_t)NTOK * 4);
  int*   topk_idx = (int*)alloc((size_t)NTOK * 256 * 4);
  float* topk_w   = (float*)alloc((size_t)NTOK * 256 * 4);
  size_t per_slot = (size_t)NTOK * NTILES * 4;
  int slots = (int)((ws_size - off) / per_slot);
  if (slots > 20) slots = 20;
  if (slots < 8) slots = 8;
  unsigned int* cand = (unsigned int*)alloc((size_t)NTOK * NTILES * slots * 4);

  k_cvt_bf16<<<1024, 256, 0, stream>>>(x, x_bf);
  k_cvt_bf16<<<(POOLN * DDIM) / 1024, 256, 0, stream>>>(pool, pool_bf);
  k_transpose_bf16<<<dim3(CHIDN / 64, DDIM / 64), 256, 0, stream>>>(Wc1, wc1t, DDIM, CHIDN);
  k_transpose_bf16<<<dim3(HIDN / 64, DDIM / 64), 256, 0, stream>>>(Ws1, ws1t, DDIM, HIDN);
  k_transpose_bf16<<<dim3(POOLN / 64, HIDN / 64), 256, 0, stream>>>(Ws2, ws2t, HIDN, POOLN);

  // h1 = relu(x @ Wc1 + bc1)  [2048,128]
  k_gemm<1, DDIM><<<(NTOK / 128) * (CHIDN / 128), 256, 0, stream>>>(
      x_bf, wc1t, bc1, h1_bf, NTOK, CHIDN, nullptr, nullptr, nullptr, 0);
  k_router<<<NTOK / 4, 256, 0, stream>>>(h1_bf, Wc2, bc2, budgets);

  // h = relu(x @ Ws1 + bs1)  [2048,256]
  k_gemm<1, DDIM><<<(NTOK / 128) * (HIDN / 128), 256, 0, stream>>>(
      x_bf, ws1t, bs1, h_bf, NTOK, HIDN, nullptr, nullptr, nullptr, 0);
  k_thresh<<<NTOK / 4, 256, 0, stream>>>(h_bf, T0);

  // scorer GEMM with static-slot candidate epilogue (no global atomics, no score matrix)
  k_gemm<2, HIDN><<<(NTOK / 128) * (POOLN / 128), 256, 0, stream>>>(
      h_bf, ws2t, bs2, nullptr, NTOK, POOLN, T0, counts, cand, slots);

  k_topk<<<NTOK, 256, 0, stream>>>(cand, counts, slots, budgets, topk_idx, topk_w);
  k_exec<<<NTOK, 256, 0, stream>>>(x, pool_bf, topk_idx, topk_w, budgets, out);
}